// Round 2
// baseline (560.439 us; speedup 1.0000x reference)
//
#include <hip/hip_runtime.h>
#include <hip/hip_bf16.h>
#include <stdint.h>

#define M_DIM 8192   // rows of x / out
#define K_DIM 4096   // inner dim
#define N_DIM 4096   // cols of out = rows of W

#define XB_BLOCKS 16384   // (M*K)/8/256
#define WB_BLOCKS 8192    // (N*K)/8/256

typedef __bf16 bf16x8 __attribute__((ext_vector_type(8)));
typedef float floatx4 __attribute__((ext_vector_type(4)));

__device__ __forceinline__ unsigned short f2bf_rne(float f) {
    unsigned int u = __float_as_uint(f);
    u += 0x7FFFu + ((u >> 16) & 1u);
    return (unsigned short)(u >> 16);
}

__device__ __forceinline__ unsigned short sign_bf16(float f) {
    return f > 0.f ? (unsigned short)0x3F80u
                   : (f < 0.f ? (unsigned short)0xBF80u : (unsigned short)0u);
}

// One kernel, two segments (wave-uniform branch on blockIdx):
//   blocks [0, XB_BLOCKS): x fp32 -> bf16 (RNE)
//   blocks [XB_BLOCKS, XB_BLOCKS+WB_BLOCKS): w fp32 -> sign as bf16
__global__ void cvt_fused_kernel(const float* __restrict__ x,
                                 const float* __restrict__ w,
                                 unsigned short* __restrict__ xb,
                                 unsigned short* __restrict__ wb) {
    const int b = blockIdx.x;
    if (b < XB_BLOCKS) {
        size_t t = ((size_t)b * blockDim.x + threadIdx.x) * 8;
        float4 a = *(const float4*)(x + t);
        float4 c = *(const float4*)(x + t + 4);
        union { unsigned short u[8]; uint4 v; } r;
        r.u[0] = f2bf_rne(a.x); r.u[1] = f2bf_rne(a.y);
        r.u[2] = f2bf_rne(a.z); r.u[3] = f2bf_rne(a.w);
        r.u[4] = f2bf_rne(c.x); r.u[5] = f2bf_rne(c.y);
        r.u[6] = f2bf_rne(c.z); r.u[7] = f2bf_rne(c.w);
        *(uint4*)(xb + t) = r.v;
    } else {
        size_t t = ((size_t)(b - XB_BLOCKS) * blockDim.x + threadIdx.x) * 8;
        float4 a = *(const float4*)(w + t);
        float4 c = *(const float4*)(w + t + 4);
        union { unsigned short u[8]; uint4 v; } r;
        r.u[0] = sign_bf16(a.x); r.u[1] = sign_bf16(a.y);
        r.u[2] = sign_bf16(a.z); r.u[3] = sign_bf16(a.w);
        r.u[4] = sign_bf16(c.x); r.u[5] = sign_bf16(c.y);
        r.u[6] = sign_bf16(c.z); r.u[7] = sign_bf16(c.w);
        *(uint4*)(wb + t) = r.v;
    }
}

__device__ __forceinline__ void gld_lds16(const void* g, void* l) {
    __builtin_amdgcn_global_load_lds(
        (const __attribute__((address_space(1))) void*)g,
        (__attribute__((address_space(3))) void*)l,
        16, 0, 0);
}

// C[m][n] = scale * (sum_k A[m][k]*B[n][k] + bias[n])
// A: M x K bf16 (x), B: N x K bf16 (sign weights), out fp32
// 128x128 block tile, BK=32, 4 waves in 2x2, each wave 64x64 via 4x4 MFMA 16x16x32
__global__ void __launch_bounds__(256, 4)
gemm_bt_kernel(const unsigned short* __restrict__ A,
               const unsigned short* __restrict__ B,
               const float* __restrict__ bias,
               const float* __restrict__ scale,
               float* __restrict__ out) {
    __shared__ __attribute__((aligned(16))) unsigned short sA[128 * 32];
    __shared__ __attribute__((aligned(16))) unsigned short sB[128 * 32];

    const int tid  = threadIdx.x;
    const int lane = tid & 63;
    const int wave = tid >> 6;
    const int wm = wave >> 1;   // 0..1 wave row
    const int wn = wave & 1;    // 0..1 wave col
    const int g  = lane >> 4;   // quad 0..3
    const int mn = lane & 15;

    const int rowBase = blockIdx.y * 128;
    const int colBase = blockIdx.x * 128;

    // staging: wave stages rows [wave*32, wave*32+32) of each tile,
    // 2 instrs of 1024B each (16 rows x 64B); lane -> row lane/4, 16B chunk lane%4
    const int srow   = lane >> 2;
    const int schunk = lane & 3;
    const unsigned short* gA0 =
        A + (size_t)(rowBase + wave * 32 + srow) * K_DIM + schunk * 8;
    const unsigned short* gB0 =
        B + (size_t)(colBase + wave * 32 + srow) * K_DIM + schunk * 8;
    unsigned short* lA0 = &sA[(wave * 32) * 32];
    unsigned short* lB0 = &sB[(wave * 32) * 32];

    floatx4 acc[4][4] = {};

    for (int k0 = 0; k0 < K_DIM; k0 += 32) {
        gld_lds16(gA0 + k0, lA0);
        gld_lds16(gA0 + k0 + (size_t)16 * K_DIM, lA0 + 16 * 32);
        gld_lds16(gB0 + k0, lB0);
        gld_lds16(gB0 + k0 + (size_t)16 * K_DIM, lB0 + 16 * 32);
        __syncthreads();

        bf16x8 af[4], bfr[4];
#pragma unroll
        for (int i = 0; i < 4; ++i)
            af[i] = *(const bf16x8*)(&sA[(wm * 64 + i * 16 + mn) * 32 + g * 8]);
#pragma unroll
        for (int j = 0; j < 4; ++j)
            bfr[j] = *(const bf16x8*)(&sB[(wn * 64 + j * 16 + mn) * 32 + g * 8]);

#pragma unroll
        for (int i = 0; i < 4; ++i)
#pragma unroll
            for (int j = 0; j < 4; ++j)
                acc[i][j] = __builtin_amdgcn_mfma_f32_16x16x32_bf16(
                    af[i], bfr[j], acc[i][j], 0, 0, 0);
        __syncthreads();
    }

    // epilogue: C/D layout col = lane&15, row = (lane>>4)*4 + reg
    // nontemporal stores: avoid L2 read-for-ownership on output lines
    const float s = scale[0];
#pragma unroll
    for (int j = 0; j < 4; ++j) {
        const int gcol = colBase + wn * 64 + j * 16 + mn;
        const float bv = bias[gcol];
#pragma unroll
        for (int i = 0; i < 4; ++i) {
            const int grow0 = rowBase + wm * 64 + i * 16 + g * 4;
#pragma unroll
            for (int r = 0; r < 4; ++r)
                __builtin_nontemporal_store(
                    s * (acc[i][j][r] + bv),
                    out + (size_t)(grow0 + r) * N_DIM + gcol);
        }
    }
}

// slow but correct fp32 fallback (only if workspace is too small)
__global__ void fallback_kernel(const float* __restrict__ x,
                                const float* __restrict__ w,
                                const float* __restrict__ bias,
                                const float* __restrict__ scale,
                                float* __restrict__ out) {
    int col = blockIdx.x * 64 + (threadIdx.x & 63);
    int row = blockIdx.y * 4 + (threadIdx.x >> 6);
    const float* xr = x + (size_t)row * K_DIM;
    const float* wr = w + (size_t)col * K_DIM;
    float acc = 0.f;
    for (int k = 0; k < K_DIM; k += 4) {
        float4 a = *(const float4*)(xr + k);
        float4 b = *(const float4*)(wr + k);
        acc += a.x * (b.x > 0.f ? 1.f : (b.x < 0.f ? -1.f : 0.f));
        acc += a.y * (b.y > 0.f ? 1.f : (b.y < 0.f ? -1.f : 0.f));
        acc += a.z * (b.z > 0.f ? 1.f : (b.z < 0.f ? -1.f : 0.f));
        acc += a.w * (b.w > 0.f ? 1.f : (b.w < 0.f ? -1.f : 0.f));
    }
    out[(size_t)row * N_DIM + col] = scale[0] * (acc + bias[col]);
}

extern "C" void kernel_launch(void* const* d_in, const int* in_sizes, int n_in,
                              void* d_out, int out_size, void* d_ws, size_t ws_size,
                              hipStream_t stream) {
    const float* x     = (const float*)d_in[0];
    const float* w     = (const float*)d_in[1];
    const float* bias  = (const float*)d_in[2];
    const float* scale = (const float*)d_in[3];
    float* out = (float*)d_out;

    const size_t xb_elems = (size_t)M_DIM * K_DIM;
    const size_t wb_elems = (size_t)N_DIM * K_DIM;
    const size_t need = (xb_elems + wb_elems) * sizeof(unsigned short);

    if (ws_size >= need) {
        unsigned short* xb = (unsigned short*)d_ws;
        unsigned short* wb = xb + xb_elems;
        cvt_fused_kernel<<<dim3(XB_BLOCKS + WB_BLOCKS), 256, 0, stream>>>(x, w, xb, wb);
        dim3 grid(N_DIM / 128, M_DIM / 128);
        gemm_bt_kernel<<<grid, 256, 0, stream>>>(xb, wb, bias, scale, out);
    } else {
        dim3 grid(N_DIM / 64, M_DIM / 4);
        fallback_kernel<<<grid, 256, 0, stream>>>(x, w, bias, scale, out);
    }
}

// Round 3
// 415.146 us; speedup vs baseline: 1.3500x; 1.3500x over previous
//
#include <hip/hip_runtime.h>
#include <hip/hip_bf16.h>
#include <stdint.h>

#define M_DIM 8192   // rows of x / out
#define K_DIM 4096   // inner dim
#define N_DIM 4096   // cols of out = rows of W

typedef int intx4 __attribute__((ext_vector_type(4)));

// ---------------------------------------------------------------------------
// Fused conversion:
//   blocks [0, 8192):      one block per row of x -> per-row absmax-quant i8
//   blocks [8192, 16384):  w fp32 -> sign as i8, 8 elems/thread
// ---------------------------------------------------------------------------
__global__ void cvt_fused_i8_kernel(const float* __restrict__ x,
                                    const float* __restrict__ w,
                                    signed char* __restrict__ xb,
                                    signed char* __restrict__ wb,
                                    float* __restrict__ row_scale) {
    const int b   = blockIdx.x;
    const int tid = threadIdx.x;
    if (b < M_DIM) {
        // quantize one 4096-element row of x
        __shared__ float wmax[4];
        const float* xr = x + (size_t)b * K_DIM;
        float4 v[4];
        const int base = tid * 16;
#pragma unroll
        for (int i = 0; i < 4; ++i) v[i] = *(const float4*)(xr + base + i * 4);

        float am = 0.f;
#pragma unroll
        for (int i = 0; i < 4; ++i) {
            am = fmaxf(am, fabsf(v[i].x)); am = fmaxf(am, fabsf(v[i].y));
            am = fmaxf(am, fabsf(v[i].z)); am = fmaxf(am, fabsf(v[i].w));
        }
        // wave reduce (64 lanes)
#pragma unroll
        for (int off = 32; off > 0; off >>= 1)
            am = fmaxf(am, __shfl_xor(am, off));
        if ((tid & 63) == 0) wmax[tid >> 6] = am;
        __syncthreads();
        am = fmaxf(fmaxf(wmax[0], wmax[1]), fmaxf(wmax[2], wmax[3]));
        am = fmaxf(am, 1e-30f);

        const float inv = 127.f / am;
        union { signed char c[16]; uint4 u; } r;
        const float* vf = (const float*)v;
#pragma unroll
        for (int i = 0; i < 16; ++i) {
            int q = (int)rintf(vf[i] * inv);
            q = q > 127 ? 127 : (q < -127 ? -127 : q);
            r.c[i] = (signed char)q;
        }
        *(uint4*)(xb + (size_t)b * K_DIM + base) = r.u;
        if (tid == 0) row_scale[b] = am * (1.f / 127.f);
    } else {
        // sign(w) -> i8, 8 elems/thread
        size_t t = ((size_t)(b - M_DIM) * blockDim.x + tid) * 8;
        float4 a = *(const float4*)(w + t);
        float4 c = *(const float4*)(w + t + 4);
        union { signed char s[8]; uint2 u; } r;
        r.s[0] = (a.x > 0.f) - (a.x < 0.f); r.s[1] = (a.y > 0.f) - (a.y < 0.f);
        r.s[2] = (a.z > 0.f) - (a.z < 0.f); r.s[3] = (a.w > 0.f) - (a.w < 0.f);
        r.s[4] = (c.x > 0.f) - (c.x < 0.f); r.s[5] = (c.y > 0.f) - (c.y < 0.f);
        r.s[6] = (c.z > 0.f) - (c.z < 0.f); r.s[7] = (c.w > 0.f) - (c.w < 0.f);
        *(uint2*)(wb + t) = r.u;
    }
}

__device__ __forceinline__ void gld_lds16(const void* g, void* l) {
    __builtin_amdgcn_global_load_lds(
        (const __attribute__((address_space(1))) void*)g,
        (__attribute__((address_space(3))) void*)l,
        16, 0, 0);
}

// ---------------------------------------------------------------------------
// i8 GEMM: C[m][n] = scale * (i32dot(A[m],B[n]) * row_scale[m] + bias[n])
// A: M x K i8 (quantized x), B: N x K i8 (sign weights), out fp32
// 128x128 block tile, BK=64, 4 waves 2x2, wave does 64x64 via 4x4 MFMA 16x16x64
// ---------------------------------------------------------------------------
__global__ void __launch_bounds__(256, 4)
gemm_i8_kernel(const signed char* __restrict__ A,
               const signed char* __restrict__ B,
               const float* __restrict__ bias,
               const float* __restrict__ scale,
               const float* __restrict__ row_scale,
               float* __restrict__ out) {
    __shared__ __attribute__((aligned(16))) signed char sA[128 * 64];
    __shared__ __attribute__((aligned(16))) signed char sB[128 * 64];

    const int tid  = threadIdx.x;
    const int lane = tid & 63;
    const int wave = tid >> 6;
    const int wm = wave >> 1;   // wave row 0..1
    const int wn = wave & 1;    // wave col 0..1
    const int g  = lane >> 4;   // quad 0..3
    const int mn = lane & 15;

    const int rowBase = blockIdx.y * 128;
    const int colBase = blockIdx.x * 128;

    // staging: wave stages rows [wave*32, wave*32+32); row = 64 B of i8;
    // one 1024B global_load_lds covers 16 rows; lane -> row lane/4, 16B chunk lane%4
    const int srow   = lane >> 2;
    const int schunk = lane & 3;
    const signed char* gA0 =
        A + (size_t)(rowBase + wave * 32 + srow) * K_DIM + schunk * 16;
    const signed char* gB0 =
        B + (size_t)(colBase + wave * 32 + srow) * K_DIM + schunk * 16;
    signed char* lA0 = &sA[(wave * 32) * 64];
    signed char* lB0 = &sB[(wave * 32) * 64];

    intx4 acc[4][4] = {};

    for (int k0 = 0; k0 < K_DIM; k0 += 64) {
        gld_lds16(gA0 + k0, lA0);
        gld_lds16(gA0 + k0 + (size_t)16 * K_DIM, lA0 + 16 * 64);
        gld_lds16(gB0 + k0, lB0);
        gld_lds16(gB0 + k0 + (size_t)16 * K_DIM, lB0 + 16 * 64);
        __syncthreads();

        // A-frag: lane holds A[row=mn][k = g*16 .. g*16+15] (contiguous 16 B)
        intx4 af[4], bfr[4];
#pragma unroll
        for (int i = 0; i < 4; ++i)
            af[i] = *(const intx4*)(&sA[(wm * 64 + i * 16 + mn) * 64 + g * 16]);
#pragma unroll
        for (int j = 0; j < 4; ++j)
            bfr[j] = *(const intx4*)(&sB[(wn * 64 + j * 16 + mn) * 64 + g * 16]);

#pragma unroll
        for (int i = 0; i < 4; ++i)
#pragma unroll
            for (int j = 0; j < 4; ++j)
                acc[i][j] = __builtin_amdgcn_mfma_i32_16x16x64_i8(
                    af[i], bfr[j], acc[i][j], 0, 0, 0);
        __syncthreads();
    }

    // epilogue: C/D layout col = lane&15, row = (lane>>4)*4 + reg (dtype-indep)
    const float s = scale[0];
#pragma unroll
    for (int j = 0; j < 4; ++j) {
        const int gcol = colBase + wn * 64 + j * 16 + mn;
        const float bv = bias[gcol];
#pragma unroll
        for (int i = 0; i < 4; ++i) {
            const int grow0 = rowBase + wm * 64 + i * 16 + g * 4;
            float4 rs4 = *(const float4*)(row_scale + grow0);
            float rs[4] = {rs4.x, rs4.y, rs4.z, rs4.w};
#pragma unroll
            for (int r = 0; r < 4; ++r)
                __builtin_nontemporal_store(
                    s * ((float)acc[i][j][r] * rs[r] + bv),
                    out + (size_t)(grow0 + r) * N_DIM + gcol);
        }
    }
}

// slow but correct fp32 fallback (only if workspace is too small)
__global__ void fallback_kernel(const float* __restrict__ x,
                                const float* __restrict__ w,
                                const float* __restrict__ bias,
                                const float* __restrict__ scale,
                                float* __restrict__ out) {
    int col = blockIdx.x * 64 + (threadIdx.x & 63);
    int row = blockIdx.y * 4 + (threadIdx.x >> 6);
    const float* xr = x + (size_t)row * K_DIM;
    const float* wr = w + (size_t)col * K_DIM;
    float acc = 0.f;
    for (int k = 0; k < K_DIM; k += 4) {
        float4 a = *(const float4*)(xr + k);
        float4 b = *(const float4*)(wr + k);
        acc += a.x * (b.x > 0.f ? 1.f : (b.x < 0.f ? -1.f : 0.f));
        acc += a.y * (b.y > 0.f ? 1.f : (b.y < 0.f ? -1.f : 0.f));
        acc += a.z * (b.z > 0.f ? 1.f : (b.z < 0.f ? -1.f : 0.f));
        acc += a.w * (b.w > 0.f ? 1.f : (b.w < 0.f ? -1.f : 0.f));
    }
    out[(size_t)row * N_DIM + col] = scale[0] * (acc + bias[col]);
}

extern "C" void kernel_launch(void* const* d_in, const int* in_sizes, int n_in,
                              void* d_out, int out_size, void* d_ws, size_t ws_size,
                              hipStream_t stream) {
    const float* x     = (const float*)d_in[0];
    const float* w     = (const float*)d_in[1];
    const float* bias  = (const float*)d_in[2];
    const float* scale = (const float*)d_in[3];
    float* out = (float*)d_out;

    const size_t xb_bytes = (size_t)M_DIM * K_DIM;          // 32 MiB
    const size_t wb_bytes = (size_t)N_DIM * K_DIM;          // 16 MiB
    const size_t need = xb_bytes + wb_bytes + M_DIM * sizeof(float);

    if (ws_size >= need) {
        signed char* xb = (signed char*)d_ws;
        signed char* wb = xb + xb_bytes;
        float* row_scale = (float*)(wb + wb_bytes);
        const unsigned w_blocks = (unsigned)((size_t)N_DIM * K_DIM / 8 / 256); // 8192
        cvt_fused_i8_kernel<<<dim3(M_DIM + w_blocks), 256, 0, stream>>>(
            x, w, xb, wb, row_scale);
        dim3 grid(N_DIM / 128, M_DIM / 128);
        gemm_i8_kernel<<<grid, 256, 0, stream>>>(xb, wb, bias, scale, row_scale, out);
    } else {
        dim3 grid(N_DIM / 64, M_DIM / 4);
        fallback_kernel<<<grid, 256, 0, stream>>>(x, w, bias, scale, out);
    }
}